// Round 4
// baseline (422.041 us; speedup 1.0000x reference)
//
#include <hip/hip_runtime.h>
#include <math.h>

typedef unsigned short u16;
typedef __bf16 bf16x8 __attribute__((ext_vector_type(8)));
typedef float floatx4 __attribute__((ext_vector_type(4)));
typedef float floatx16 __attribute__((ext_vector_type(16)));

#define MFMA16(a, b, c) __builtin_amdgcn_mfma_f32_16x16x32_bf16((a), (b), (c), 0, 0, 0)
#define MFMA32(a, b, c) __builtin_amdgcn_mfma_f32_32x32x16_bf16((a), (b), (c), 0, 0, 0)

__device__ __forceinline__ float bf2f(u16 u) {
  union { float f; unsigned int i; } v; v.i = ((unsigned int)u) << 16; return v.f;
}
__device__ __forceinline__ u16 f2bf(float f) {  // native RNE cvt
  __bf16 h = (__bf16)f;
  union { __bf16 h; u16 u; } v; v.h = h; return v.u;
}
__device__ __forceinline__ bf16x8 cvt8(float4 a, float4 b) {
  bf16x8 r;
  r[0] = (__bf16)a.x; r[1] = (__bf16)a.y; r[2] = (__bf16)a.z; r[3] = (__bf16)a.w;
  r[4] = (__bf16)b.x; r[5] = (__bf16)b.y; r[6] = (__bf16)b.z; r[7] = (__bf16)b.w;
  return r;
}
// Async global->LDS, 16 B per lane. LDS dest = wave-uniform base + lane*16.
__device__ __forceinline__ void gl2lds16(const void* g, void* l) {
  __builtin_amdgcn_global_load_lds(
      (const __attribute__((address_space(1))) unsigned int*)g,
      (__attribute__((address_space(3))) unsigned int*)l, 16, 0, 0);
}

struct GemmArgs {
  const void* A[3];     // fp32 (ABF16=0) or bf16 (ABF16=1) [.,1024]
  const float* W[3];    // fp32 [1024,1024] used as B^T (NT)
  const float* bias[3]; // fp32 [1024]
  void* C[3];
  int out_mode[3];      // 0 = bf16, 1 = bf16 Vt[b,h,d,s], 2 = fp32
};

// C[4096,1024] = A @ W^T + bias, BMx128 tile, BK=32, fp32 acc.
// Staging via global_load_lds (16B/lane); fp32 tiles converted to bf16 at
// fragment-read with native cvt. 16B chunks XOR-swizzled -> conflict-free b128.
template <int BM, int ABF16>
__global__ __launch_bounds__(256) void gemm_nt(GemmArgs args) {
  const int N = 1024, K = 1024;
  const int z = blockIdx.z;
  const float* W = args.W[z];
  const float* bias = args.bias[z];
  const int out_mode = args.out_mode[z];
  constexpr int MI = BM / 32;

  __shared__ __align__(16) char AsB[ABF16 ? BM * 64 : BM * 128];
  __shared__ __align__(16) char BsB[128 * 128];

  const int t = threadIdx.x;
  const int wave = t >> 6, lane = t & 63;
  const int lr = lane & 15, quad = lane >> 4;
  const int wm = (wave >> 1) * (BM / 2), wn = (wave & 1) * 64;
  const int m0 = blockIdx.y * BM, n0 = blockIdx.x * 128;

  floatx4 acc[MI][4] = {};

  for (int kt = 0; kt < K; kt += 32) {
    __syncthreads();
    if constexpr (ABF16) {
      const u16* Ab = (const u16*)args.A[z];
#pragma unroll
      for (int j = 0; j < BM / 64; j++) {
        const int r0 = wave * (BM / 4) + j * 16;
        const int row = r0 + (lane >> 2);
        const int cg = (lane & 3) ^ ((lane >> 2) & 3);
        gl2lds16(Ab + (size_t)(m0 + row) * K + kt + cg * 8, AsB + r0 * 64 + lane * 16);
      }
    } else {
      const float* Af = (const float*)args.A[z];
#pragma unroll
      for (int j = 0; j < BM / 32; j++) {
        const int r0 = wave * (BM / 4) + j * 8;
        const int row = r0 + (lane >> 3);
        const int cg = (lane & 7) ^ ((lane >> 3) & 7);
        gl2lds16(Af + (size_t)(m0 + row) * K + kt + cg * 4, AsB + r0 * 128 + lane * 16);
      }
    }
#pragma unroll
    for (int j = 0; j < 4; j++) {
      const int r0 = wave * 32 + j * 8;
      const int row = r0 + (lane >> 3);
      const int cg = (lane & 7) ^ ((lane >> 3) & 7);
      gl2lds16(W + (size_t)(n0 + row) * K + kt + cg * 4, BsB + r0 * 128 + lane * 16);
    }
    __syncthreads();

    bf16x8 af[MI], bf[4];
#pragma unroll
    for (int i = 0; i < MI; i++) {
      const int row = wm + i * 16 + lr;
      if constexpr (ABF16) {
        const int cp = quad ^ (row & 3);
        af[i] = *reinterpret_cast<const bf16x8*>(AsB + row * 64 + cp * 16);
      } else {
        const int e = row & 7;
        const float4 c0 = *reinterpret_cast<const float4*>(AsB + row * 128 + ((2 * quad) ^ e) * 16);
        const float4 c1 = *reinterpret_cast<const float4*>(AsB + row * 128 + ((2 * quad + 1) ^ e) * 16);
        af[i] = cvt8(c0, c1);
      }
    }
#pragma unroll
    for (int i = 0; i < 4; i++) {
      const int row = wn + i * 16 + lr;
      const int e = row & 7;
      const float4 c0 = *reinterpret_cast<const float4*>(BsB + row * 128 + ((2 * quad) ^ e) * 16);
      const float4 c1 = *reinterpret_cast<const float4*>(BsB + row * 128 + ((2 * quad + 1) ^ e) * 16);
      bf[i] = cvt8(c0, c1);
    }
#pragma unroll
    for (int mi = 0; mi < MI; mi++)
#pragma unroll
      for (int nf = 0; nf < 4; nf++)
        acc[mi][nf] = MFMA16(af[mi], bf[nf], acc[mi][nf]);
  }

  // epilogue: C-frag col = lane&15, row = quad*4 + reg
#pragma unroll
  for (int nf = 0; nf < 4; nf++) {
    const int col = n0 + wn + nf * 16 + lr;
    const float bv = bias[col];
#pragma unroll
    for (int mi = 0; mi < MI; mi++) {
      const int row0 = m0 + wm + mi * 16 + quad * 4;
      if (out_mode == 0) {
        u16* C = (u16*)args.C[z];
#pragma unroll
        for (int r = 0; r < 4; r++)
          C[(row0 + r) * N + col] = f2bf(acc[mi][nf][r] + bv);
      } else if (out_mode == 1) {
        u16* C = (u16*)args.C[z];
        const int h = col >> 6, d = col & 63;
        const int b = row0 >> 11, s = row0 & 2047;
        ushort4 pk;
        pk.x = f2bf(acc[mi][nf][0] + bv);
        pk.y = f2bf(acc[mi][nf][1] + bv);
        pk.z = f2bf(acc[mi][nf][2] + bv);
        pk.w = f2bf(acc[mi][nf][3] + bv);
        *reinterpret_cast<ushort4*>(&C[((b * 16 + h) * 64 + d) * 2048 + s]) = pk;
      } else {
        float* C = (float*)args.C[z];
#pragma unroll
        for (int r = 0; r < 4; r++)
          C[(row0 + r) * N + col] = acc[mi][nf][r] + bv;
      }
    }
  }
}

// Interleaved RoPE on Q and K in-place (bf16).
// Q gets scale 0.125*log2(e): folds 1/sqrt(D) AND the exp->exp2 domain switch
// used by the in-register softmax in attn_kernel.
__global__ __launch_bounds__(256) void rope_kernel(u16* Q, u16* Kb) {
  const int idx = blockIdx.x * 256 + threadIdx.x;
  const int tensor = idx >> 19;
  const int i = idx & 524287;
  u16* P = tensor ? Kb : Q;
  const int row = i >> 7;
  const int cg = i & 127;
  const int s = row & 2047;
  const int col0 = cg * 8;
  const float scale = tensor ? 1.0f : 0.18033688011112042f;  // 0.125 * log2(e)
  union { uint4 u; u16 h[8]; } v;
  v.u = *reinterpret_cast<const uint4*>(&P[row * 1024 + col0]);
  const int j0 = (col0 & 63) >> 1;
#pragma unroll
  for (int p = 0; p < 4; p++) {
    const int j = j0 + p;
    const float inv = exp2f(-(float)j * (13.287712379549449f / 32.0f));  // 10000^(-j/32)
    const float f = (float)s * inv;
    float sn, cs;
    sincosf(f, &sn, &cs);
    const float e = bf2f(v.h[2 * p]), o = bf2f(v.h[2 * p + 1]);
    v.h[2 * p]     = f2bf((e * cs - o * sn) * scale);
    v.h[2 * p + 1] = f2bf((o * cs + e * sn) * scale);
  }
  *reinterpret_cast<uint4*>(&P[row * 1024 + col0]) = v.u;
}

// P^T fragment build: regs g..g+7 of a 32-reg S^T acc hold
// k = base + (r&3) + 8*(r>>2) + 4*hi (hi = lane>>5), q = lane&31.
// B-operand of mfma32 needs lane to hold k = base + 8*hi + j (j=0..7).
// cvt_pk pairs + v_permlane32_swap_b32 (dst' = [dst.lo, src.lo],
// src' = [dst.hi, src.hi]; partner lane l^32 has the SAME q) produce exactly
// that: wA'=j{0,1}, wC'=j{2,3}, wB'=j{4,5}, wD'=j{6,7}.
#define MAKE_PB(pp, g, out) do {                                              \
    unsigned int wA, wB, wC, wD;                                              \
    asm("v_cvt_pk_bf16_f32 %0, %1, %2" : "=v"(wA) : "v"((pp)[(g)+0]), "v"((pp)[(g)+1])); \
    asm("v_cvt_pk_bf16_f32 %0, %1, %2" : "=v"(wB) : "v"((pp)[(g)+4]), "v"((pp)[(g)+5])); \
    asm("v_cvt_pk_bf16_f32 %0, %1, %2" : "=v"(wC) : "v"((pp)[(g)+2]), "v"((pp)[(g)+3])); \
    asm("v_cvt_pk_bf16_f32 %0, %1, %2" : "=v"(wD) : "v"((pp)[(g)+6]), "v"((pp)[(g)+7])); \
    asm("v_permlane32_swap_b32 %0, %1" : "+v"(wA), "+v"(wB));                 \
    asm("v_permlane32_swap_b32 %0, %1" : "+v"(wC), "+v"(wD));                 \
    union { unsigned int w[4]; bf16x8 v; } u_;                                \
    u_.w[0] = wA; u_.w[1] = wC; u_.w[2] = wB; u_.w[3] = wD;                   \
    (out) = u_.v;                                                             \
  } while (0)

// Flash attention v4 (R3): R2's swapped-operand in-register structure
// + 2-way K-split for TLP (R3 diagnosis: latency-bound at 20% occupancy,
// grid = 2 waves/SIMD). 8 warps/block = 4 q-tiles x 2 k-halves; each warp
// covers 1024 KV positions; warp pairs merge (m, l, O) once at the end via
// LDS (2 barriers + 34 KB, amortized over 32 tiles). Main loop unchanged:
// no LDS, no barriers, direct L2-resident K/V reads, prefetch-after-use.
__global__ __launch_bounds__(512, 4) void attn_kernel(const u16* Q, const u16* K,
                                                      const u16* Vt, u16* O) {
  const int bh = blockIdx.y;
  const int b = bh >> 4, h = bh & 15;
  const int t = threadIdx.x;
  const int warp = t >> 6, lane = t & 63;
  const int lq = lane & 31, hi = lane >> 5;
  const int pair = warp >> 1, w = warp & 1;

  __shared__ float Mlm[4][2][32];
  __shared__ float Mll[4][2][32];
  __shared__ __align__(16) float Ox[4][32][64];

  const int q0 = (blockIdx.x * 4 + pair) * 32;
  const int k0 = w * 1024;  // this warp's KV half

  // Q B-frag: qf[s][j] = Q[q0+lq][h*64 + 16s + 8hi + j]
  const u16* qp = &Q[(size_t)(b * 2048 + q0 + lq) * 1024 + h * 64 + hi * 8];
  bf16x8 qf[4];
#pragma unroll
  for (int s = 0; s < 4; s++) qf[s] = *reinterpret_cast<const bf16x8*>(&qp[s * 16]);

  // K A-frag: kf[kb][s][j] = K[kt + 32kb + lq][h*64 + 16s + 8hi + j]
  const u16* kp = &K[(size_t)(b * 2048 + lq) * 1024 + h * 64 + hi * 8];
  // Vt A-frag: vf[ks][dblk][j] = Vt[bh][32dblk + lq][kt + 16ks + 8hi + j]
  const u16* vp = &Vt[(size_t)bh * 131072 + (size_t)lq * 2048 + hi * 8];

  bf16x8 kf[2][4], vf[4][2];
#pragma unroll
  for (int kb = 0; kb < 2; kb++)
#pragma unroll
    for (int s = 0; s < 4; s++)
      kf[kb][s] = *reinterpret_cast<const bf16x8*>(&kp[(size_t)(k0 + kb * 32) * 1024 + s * 16]);
#pragma unroll
  for (int ks = 0; ks < 4; ks++)
#pragma unroll
    for (int d = 0; d < 2; d++)
      vf[ks][d] = *reinterpret_cast<const bf16x8*>(&vp[(size_t)d * 65536 + k0 + ks * 16]);

  floatx16 o0 = {}, o1 = {};
  float m = -1.0e30f, l = 0.0f;

  for (int kt = k0; kt < k0 + 1024; kt += 64) {
    const int ktn = k0 + ((kt + 64 - k0) & 1023);  // wrap: last prefetch discarded

    // QK^T: p0/p1 reg r = S^T[k = kt + 32kb + (r&3)+8*(r>>2)+4hi][q0+lq]
    floatx16 p0 = {}, p1 = {};
#pragma unroll
    for (int s = 0; s < 4; s++) {
      p0 = MFMA32(kf[0][s], qf[s], p0);
      p1 = MFMA32(kf[1][s], qf[s], p1);
    }
    // prefetch K(t+1): overlaps softmax + PV
#pragma unroll
    for (int kb = 0; kb < 2; kb++)
#pragma unroll
      for (int s = 0; s < 4; s++)
        kf[kb][s] = *reinterpret_cast<const bf16x8*>(
            &kp[(size_t)(ktn + kb * 32) * 1024 + s * 16]);

    // online softmax (log2 domain), q = lq lane-local; partner l^32 has other 32 k
    float mx = p0[0];
#pragma unroll
    for (int r = 1; r < 16; r++) mx = fmaxf(mx, p0[r]);
#pragma unroll
    for (int r = 0; r < 16; r++) mx = fmaxf(mx, p1[r]);
    mx = fmaxf(mx, __shfl_xor(mx, 32, 64));
    if (!__all(mx <= m + 10.0f)) {  // defer-max: P bounded by 2^10
      const float mn = fmaxf(m, mx);
      const float al = __builtin_amdgcn_exp2f(m - mn);
      m = mn;
      l *= al;
#pragma unroll
      for (int r = 0; r < 16; r++) { o0[r] *= al; o1[r] *= al; }
    }
    float sum = 0.0f;
#pragma unroll
    for (int r = 0; r < 16; r++) { p0[r] = __builtin_amdgcn_exp2f(p0[r] - m); sum += p0[r]; }
#pragma unroll
    for (int r = 0; r < 16; r++) { p1[r] = __builtin_amdgcn_exp2f(p1[r] - m); sum += p1[r]; }
    l += sum + __shfl_xor(sum, 32, 64);

    // P^T -> bf16 B-frags (in-register)
    bf16x8 pb0, pb1, pb2, pb3;
    MAKE_PB(p0, 0, pb0);
    MAKE_PB(p0, 8, pb1);
    MAKE_PB(p1, 0, pb2);
    MAKE_PB(p1, 8, pb3);

    // PV: O^T += Vt @ P^T
    o0 = MFMA32(vf[0][0], pb0, o0);
    o1 = MFMA32(vf[0][1], pb0, o1);
    o0 = MFMA32(vf[1][0], pb1, o0);
    o1 = MFMA32(vf[1][1], pb1, o1);
    o0 = MFMA32(vf[2][0], pb2, o0);
    o1 = MFMA32(vf[2][1], pb2, o1);
    o0 = MFMA32(vf[3][0], pb3, o0);
    o1 = MFMA32(vf[3][1], pb3, o1);

    // prefetch V(t+1): overlaps next tile's QK^T + softmax
#pragma unroll
    for (int ks = 0; ks < 4; ks++)
#pragma unroll
      for (int d = 0; d < 2; d++)
        vf[ks][d] = *reinterpret_cast<const bf16x8*>(
            &vp[(size_t)d * 65536 + ktn + ks * 16]);
  }

  // ---- k-split merge: combine (m, l, O) across the warp pair ----
  if (hi == 0) { Mlm[pair][w][lq] = m; Mll[pair][w][lq] = l; }
  __syncthreads();
  const float mo = Mlm[pair][w ^ 1][lq];
  const float lo = Mll[pair][w ^ 1][lq];
  const float ms = fmaxf(m, mo);
  const float f  = __builtin_amdgcn_exp2f(m - ms);
  const float fo = __builtin_amdgcn_exp2f(mo - ms);
  const float ltot = l * f + lo * fo;
  if (w == 1) {
#pragma unroll
    for (int r = 0; r < 16; r++) {
      Ox[pair][r][lane] = o0[r] * f;
      Ox[pair][16 + r][lane] = o1[r] * f;
    }
  }
  __syncthreads();
  if (w == 0) {
    // epilogue: O^T reg r -> d = (r&3) + 8*(r>>2) + 4hi + 32*dblk, q = q0+lq
    const float rl = 1.0f / ltot;
    u16* op = &O[(size_t)(b * 2048 + q0 + lq) * 1024 + h * 64 + hi * 4];
#pragma unroll
    for (int rq = 0; rq < 4; rq++) {
      ushort4 s0, s1;
      s0.x = f2bf((o0[4 * rq + 0] * f + Ox[pair][4 * rq + 0][lane]) * rl);
      s0.y = f2bf((o0[4 * rq + 1] * f + Ox[pair][4 * rq + 1][lane]) * rl);
      s0.z = f2bf((o0[4 * rq + 2] * f + Ox[pair][4 * rq + 2][lane]) * rl);
      s0.w = f2bf((o0[4 * rq + 3] * f + Ox[pair][4 * rq + 3][lane]) * rl);
      s1.x = f2bf((o1[4 * rq + 0] * f + Ox[pair][16 + 4 * rq + 0][lane]) * rl);
      s1.y = f2bf((o1[4 * rq + 1] * f + Ox[pair][16 + 4 * rq + 1][lane]) * rl);
      s1.z = f2bf((o1[4 * rq + 2] * f + Ox[pair][16 + 4 * rq + 2][lane]) * rl);
      s1.w = f2bf((o1[4 * rq + 3] * f + Ox[pair][16 + 4 * rq + 3][lane]) * rl);
      *reinterpret_cast<ushort4*>(&op[rq * 8]) = s0;
      *reinterpret_cast<ushort4*>(&op[rq * 8 + 32]) = s1;
    }
  }
}

extern "C" void kernel_launch(void* const* d_in, const int* in_sizes, int n_in,
                              void* d_out, int out_size, void* d_ws, size_t ws_size,
                              hipStream_t stream) {
  (void)in_sizes; (void)n_in; (void)out_size; (void)ws_size;
  const float* query = (const float*)d_in[0];
  const float* key   = (const float*)d_in[1];
  const float* value = (const float*)d_in[2];
  const float* Wq = (const float*)d_in[3];
  const float* bq = (const float*)d_in[4];
  const float* Wk = (const float*)d_in[5];
  const float* bk = (const float*)d_in[6];
  const float* Wv = (const float*)d_in[7];
  const float* bv = (const float*)d_in[8];
  const float* Wo = (const float*)d_in[9];
  const float* bo = (const float*)d_in[10];

  // Qb (8 MB bf16) in ws; Kb + Vt (16 MB bf16) inside d_out (16 MB fp32),
  // dead until the final fp32 GEMM overwrites it.
  u16* Qb = (u16*)d_ws;
  u16* Kb = (u16*)d_out;
  u16* Vt = (u16*)d_out + 4194304;

  GemmArgs g1;
  g1.A[0] = query; g1.W[0] = Wq; g1.bias[0] = bq; g1.C[0] = Qb; g1.out_mode[0] = 0;
  g1.A[1] = key;   g1.W[1] = Wk; g1.bias[1] = bk; g1.C[1] = Kb; g1.out_mode[1] = 0;
  g1.A[2] = value; g1.W[2] = Wv; g1.bias[2] = bv; g1.C[2] = Vt; g1.out_mode[2] = 1;
  gemm_nt<128, 0><<<dim3(8, 32, 3), dim3(256), 0, stream>>>(g1);

  rope_kernel<<<dim3(4096), dim3(256), 0, stream>>>(Qb, Kb);

  attn_kernel<<<dim3(16, 32), dim3(512), 0, stream>>>(Qb, Kb, Vt, Qb);

  // Final projection: bf16 attn output -> fp32 d_out. BM=64 -> 512 blocks.
  GemmArgs g2;
  for (int i = 0; i < 3; i++) {
    g2.A[i] = Qb; g2.W[i] = Wo; g2.bias[i] = bo;
    g2.C[i] = d_out; g2.out_mode[i] = 2;
  }
  gemm_nt<64, 1><<<dim3(8, 64, 1), dim3(256), 0, stream>>>(g2);
}

// Round 5
// 261.310 us; speedup vs baseline: 1.6151x; 1.6151x over previous
//
#include <hip/hip_runtime.h>
#include <math.h>

typedef unsigned short u16;
typedef __bf16 bf16x8 __attribute__((ext_vector_type(8)));
typedef float floatx4 __attribute__((ext_vector_type(4)));
typedef float floatx16 __attribute__((ext_vector_type(16)));

#define MFMA16(a, b, c) __builtin_amdgcn_mfma_f32_16x16x32_bf16((a), (b), (c), 0, 0, 0)
#define MFMA32(a, b, c) __builtin_amdgcn_mfma_f32_32x32x16_bf16((a), (b), (c), 0, 0, 0)

__device__ __forceinline__ float bf2f(u16 u) {
  union { float f; unsigned int i; } v; v.i = ((unsigned int)u) << 16; return v.f;
}
__device__ __forceinline__ u16 f2bf(float f) {  // native RNE cvt
  __bf16 h = (__bf16)f;
  union { __bf16 h; u16 u; } v; v.h = h; return v.u;
}
__device__ __forceinline__ bf16x8 cvt8(float4 a, float4 b) {
  bf16x8 r;
  r[0] = (__bf16)a.x; r[1] = (__bf16)a.y; r[2] = (__bf16)a.z; r[3] = (__bf16)a.w;
  r[4] = (__bf16)b.x; r[5] = (__bf16)b.y; r[6] = (__bf16)b.z; r[7] = (__bf16)b.w;
  return r;
}
// Async global->LDS, 16 B per lane. LDS dest = wave-uniform base + lane*16.
__device__ __forceinline__ void gl2lds16(const void* g, void* l) {
  __builtin_amdgcn_global_load_lds(
      (const __attribute__((address_space(1))) unsigned int*)g,
      (__attribute__((address_space(3))) unsigned int*)l, 16, 0, 0);
}

struct GemmArgs {
  const void* A[3];     // fp32 (ABF16=0) or bf16 (ABF16=1) [.,1024]
  const float* W[3];    // fp32 [1024,1024] used as B^T (NT)
  const float* bias[3]; // fp32 [1024]
  void* C[3];
  int out_mode[3];      // 0 = bf16, 1 = bf16 Vt[b,h,d,s], 2 = fp32
};

// C[4096,1024] = A @ W^T + bias, BMx128 tile, BK=32, fp32 acc.
// Staging via global_load_lds (16B/lane); fp32 tiles converted to bf16 at
// fragment-read with native cvt. 16B chunks XOR-swizzled -> conflict-free b128.
template <int BM, int ABF16>
__global__ __launch_bounds__(256) void gemm_nt(GemmArgs args) {
  const int N = 1024, K = 1024;
  const int z = blockIdx.z;
  const float* W = args.W[z];
  const float* bias = args.bias[z];
  const int out_mode = args.out_mode[z];
  constexpr int MI = BM / 32;

  __shared__ __align__(16) char AsB[ABF16 ? BM * 64 : BM * 128];
  __shared__ __align__(16) char BsB[128 * 128];

  const int t = threadIdx.x;
  const int wave = t >> 6, lane = t & 63;
  const int lr = lane & 15, quad = lane >> 4;
  const int wm = (wave >> 1) * (BM / 2), wn = (wave & 1) * 64;
  const int m0 = blockIdx.y * BM, n0 = blockIdx.x * 128;

  floatx4 acc[MI][4] = {};

  for (int kt = 0; kt < K; kt += 32) {
    __syncthreads();
    if constexpr (ABF16) {
      const u16* Ab = (const u16*)args.A[z];
#pragma unroll
      for (int j = 0; j < BM / 64; j++) {
        const int r0 = wave * (BM / 4) + j * 16;
        const int row = r0 + (lane >> 2);
        const int cg = (lane & 3) ^ ((lane >> 2) & 3);
        gl2lds16(Ab + (size_t)(m0 + row) * K + kt + cg * 8, AsB + r0 * 64 + lane * 16);
      }
    } else {
      const float* Af = (const float*)args.A[z];
#pragma unroll
      for (int j = 0; j < BM / 32; j++) {
        const int r0 = wave * (BM / 4) + j * 8;
        const int row = r0 + (lane >> 3);
        const int cg = (lane & 7) ^ ((lane >> 3) & 7);
        gl2lds16(Af + (size_t)(m0 + row) * K + kt + cg * 4, AsB + r0 * 128 + lane * 16);
      }
    }
#pragma unroll
    for (int j = 0; j < 4; j++) {
      const int r0 = wave * 32 + j * 8;
      const int row = r0 + (lane >> 3);
      const int cg = (lane & 7) ^ ((lane >> 3) & 7);
      gl2lds16(W + (size_t)(n0 + row) * K + kt + cg * 4, BsB + r0 * 128 + lane * 16);
    }
    __syncthreads();

    bf16x8 af[MI], bf[4];
#pragma unroll
    for (int i = 0; i < MI; i++) {
      const int row = wm + i * 16 + lr;
      if constexpr (ABF16) {
        const int cp = quad ^ (row & 3);
        af[i] = *reinterpret_cast<const bf16x8*>(AsB + row * 64 + cp * 16);
      } else {
        const int e = row & 7;
        const float4 c0 = *reinterpret_cast<const float4*>(AsB + row * 128 + ((2 * quad) ^ e) * 16);
        const float4 c1 = *reinterpret_cast<const float4*>(AsB + row * 128 + ((2 * quad + 1) ^ e) * 16);
        af[i] = cvt8(c0, c1);
      }
    }
#pragma unroll
    for (int i = 0; i < 4; i++) {
      const int row = wn + i * 16 + lr;
      const int e = row & 7;
      const float4 c0 = *reinterpret_cast<const float4*>(BsB + row * 128 + ((2 * quad) ^ e) * 16);
      const float4 c1 = *reinterpret_cast<const float4*>(BsB + row * 128 + ((2 * quad + 1) ^ e) * 16);
      bf[i] = cvt8(c0, c1);
    }
#pragma unroll
    for (int mi = 0; mi < MI; mi++)
#pragma unroll
      for (int nf = 0; nf < 4; nf++)
        acc[mi][nf] = MFMA16(af[mi], bf[nf], acc[mi][nf]);
  }

  // epilogue: C-frag col = lane&15, row = quad*4 + reg
#pragma unroll
  for (int nf = 0; nf < 4; nf++) {
    const int col = n0 + wn + nf * 16 + lr;
    const float bv = bias[col];
#pragma unroll
    for (int mi = 0; mi < MI; mi++) {
      const int row0 = m0 + wm + mi * 16 + quad * 4;
      if (out_mode == 0) {
        u16* C = (u16*)args.C[z];
#pragma unroll
        for (int r = 0; r < 4; r++)
          C[(row0 + r) * N + col] = f2bf(acc[mi][nf][r] + bv);
      } else if (out_mode == 1) {
        u16* C = (u16*)args.C[z];
        const int h = col >> 6, d = col & 63;
        const int b = row0 >> 11, s = row0 & 2047;
        ushort4 pk;
        pk.x = f2bf(acc[mi][nf][0] + bv);
        pk.y = f2bf(acc[mi][nf][1] + bv);
        pk.z = f2bf(acc[mi][nf][2] + bv);
        pk.w = f2bf(acc[mi][nf][3] + bv);
        *reinterpret_cast<ushort4*>(&C[((b * 16 + h) * 64 + d) * 2048 + s]) = pk;
      } else {
        float* C = (float*)args.C[z];
#pragma unroll
        for (int r = 0; r < 4; r++)
          C[(row0 + r) * N + col] = acc[mi][nf][r] + bv;
      }
    }
  }
}

// Interleaved RoPE on Q and K in-place (bf16).
// Q gets scale 0.125*log2(e): folds 1/sqrt(D) AND the exp->exp2 domain switch
// used by the in-register softmax in attn_kernel.
__global__ __launch_bounds__(256) void rope_kernel(u16* Q, u16* Kb) {
  const int idx = blockIdx.x * 256 + threadIdx.x;
  const int tensor = idx >> 19;
  const int i = idx & 524287;
  u16* P = tensor ? Kb : Q;
  const int row = i >> 7;
  const int cg = i & 127;
  const int s = row & 2047;
  const int col0 = cg * 8;
  const float scale = tensor ? 1.0f : 0.18033688011112042f;  // 0.125 * log2(e)
  union { uint4 u; u16 h[8]; } v;
  v.u = *reinterpret_cast<const uint4*>(&P[row * 1024 + col0]);
  const int j0 = (col0 & 63) >> 1;
#pragma unroll
  for (int p = 0; p < 4; p++) {
    const int j = j0 + p;
    const float inv = exp2f(-(float)j * (13.287712379549449f / 32.0f));  // 10000^(-j/32)
    const float f = (float)s * inv;
    float sn, cs;
    sincosf(f, &sn, &cs);
    const float e = bf2f(v.h[2 * p]), o = bf2f(v.h[2 * p + 1]);
    v.h[2 * p]     = f2bf((e * cs - o * sn) * scale);
    v.h[2 * p + 1] = f2bf((o * cs + e * sn) * scale);
  }
  *reinterpret_cast<uint4*>(&P[row * 1024 + col0]) = v.u;
}

// P^T fragment build: regs g..g+7 of a 32-reg S^T acc hold
// k = base + (r&3) + 8*(r>>2) + 4*hi (hi = lane>>5), q = lane&31.
// B-operand of mfma32 needs lane to hold k = base + 8*hi + j (j=0..7).
// cvt_pk pairs + v_permlane32_swap_b32 (dst' = [dst.lo, src.lo],
// src' = [dst.hi, src.hi]; partner lane l^32 has the SAME q) produce exactly
// that: wA'=j{0,1}, wC'=j{2,3}, wB'=j{4,5}, wD'=j{6,7}.
#define MAKE_PB(pp, g, out) do {                                              \
    unsigned int wA, wB, wC, wD;                                              \
    asm("v_cvt_pk_bf16_f32 %0, %1, %2" : "=v"(wA) : "v"((pp)[(g)+0]), "v"((pp)[(g)+1])); \
    asm("v_cvt_pk_bf16_f32 %0, %1, %2" : "=v"(wB) : "v"((pp)[(g)+4]), "v"((pp)[(g)+5])); \
    asm("v_cvt_pk_bf16_f32 %0, %1, %2" : "=v"(wC) : "v"((pp)[(g)+2]), "v"((pp)[(g)+3])); \
    asm("v_cvt_pk_bf16_f32 %0, %1, %2" : "=v"(wD) : "v"((pp)[(g)+6]), "v"((pp)[(g)+7])); \
    asm("v_permlane32_swap_b32 %0, %1" : "+v"(wA), "+v"(wB));                 \
    asm("v_permlane32_swap_b32 %0, %1" : "+v"(wC), "+v"(wD));                 \
    union { unsigned int w[4]; bf16x8 v; } u_;                                \
    u_.w[0] = wA; u_.w[1] = wC; u_.w[2] = wB; u_.w[3] = wD;                   \
    (out) = u_.v;                                                             \
  } while (0)

// Flash attention v5 (R4 post-mortem): R2's swapped-operand in-register
// compute + R1's coalesced LDS staging.
// R3 diagnosis revisited: direct-from-global frags = 64 cache lines per
// wave-load -> VMEM transaction-throughput bound (~262K lines/CU ~= measured
// 129us). R4's 512-thr launch_bounds capped VGPR at 64 -> scratch spills
// (WRITE_SIZE 218 MB). Fix: stage K[64][64] + V[64][64] per block via
// global_load_lds (coalesced, each line fetched once per block, shared by
// 4 warps), double-buffered, both-sides XOR swizzle (R1's, measured 0
// conflicts), 1 barrier/tile. Compute unchanged from R3 (no k-split).
// LDS 32 KB; grid 16x32 = 2 blocks/CU; launch_bounds(256,2) -> no spills.
__global__ __launch_bounds__(256, 2) void attn_kernel(const u16* Q, const u16* K,
                                                      const u16* Vt, u16* O) {
  const int bh = blockIdx.y;
  const int b = bh >> 4, h = bh & 15;
  const int t = threadIdx.x;
  const int warp = t >> 6, lane = t & 63;
  const int lq = lane & 31, hi = lane >> 5;

  __shared__ __align__(16) u16 Ks[2][64][64];
  __shared__ __align__(16) u16 Vs[2][64][64];

  const int q0 = blockIdx.x * 128 + warp * 32;

  // Q B-frag: qf[s][j] = Q[q0+lq][h*64 + 16s + 8hi + j]
  const u16* qp = &Q[(size_t)(b * 2048 + q0 + lq) * 1024 + h * 64 + hi * 8];
  bf16x8 qf[4];
#pragma unroll
  for (int s = 0; s < 4; s++) qf[s] = *reinterpret_cast<const bf16x8*>(&qp[s * 16]);

  const u16* kbase = &K[(size_t)b * 2048 * 1024 + h * 64];
  const u16* vbase = &Vt[(size_t)bh * 131072];

  // Staging (R1 scheme): lane l writes LDS granule (l&7) of row base+(l>>3);
  // source granule pre-swizzled (l&7)^(l>>3) => LDS granule g of row r holds
  // logical granule g^(r&7). Each warp stages 16 K-rows + 16 V-rows per tile.
  const int srr = lane >> 3;            // 0..7 == dest row & 7
  const int scg = (lane & 7) ^ srr;     // swizzled source granule

  auto stage = [&](int kt2, int bufi) {
#pragma unroll
    for (int j = 0; j < 2; j++) {
      const int r0 = warp * 16 + j * 8;
      const int row = r0 + srr;
      gl2lds16(kbase + (size_t)(kt2 + row) * 1024 + scg * 8, &Ks[bufi][r0][0]);
      gl2lds16(vbase + (size_t)row * 2048 + kt2 + scg * 8, &Vs[bufi][r0][0]);
    }
  };

  floatx16 o0 = {}, o1 = {};
  float m = -1.0e30f, l = 0.0f;

  stage(0, 0);
  int buf = 0;
  for (int kt = 0; kt < 2048; kt += 64) {
    __syncthreads();  // drains vmcnt(0): stage(cur) done; prev-buf reads done (lgkm)
    if (kt + 64 < 2048) stage(kt + 64, buf ^ 1);  // async prefetch overlaps compute

    // K A-frag: kf[kb][s][j] = K[kt+32kb+lq][h*64+16s+8hi+j]
    // LDS row r = 32kb+lq, logical granule g = 2s+hi, swizzled g^(r&7).
    bf16x8 kf[2][4], vf[4][2];
#pragma unroll
    for (int kb = 0; kb < 2; kb++) {
      const int r = kb * 32 + lq;
#pragma unroll
      for (int s = 0; s < 4; s++)
        kf[kb][s] = *reinterpret_cast<const bf16x8*>(&Ks[buf][r][((s * 2 + hi) ^ (r & 7)) * 8]);
    }
    // Vt A-frag: vf[ks][d][j] = Vt[32d+lq][kt+16ks+8hi+j]
#pragma unroll
    for (int d = 0; d < 2; d++) {
      const int r = d * 32 + lq;
#pragma unroll
      for (int ks = 0; ks < 4; ks++)
        vf[ks][d] = *reinterpret_cast<const bf16x8*>(&Vs[buf][r][((ks * 2 + hi) ^ (r & 7)) * 8]);
    }

    // QK^T: p0/p1 reg r = S^T[k = kt + 32kb + (r&3)+8*(r>>2)+4hi][q0+lq]
    floatx16 p0 = {}, p1 = {};
#pragma unroll
    for (int s = 0; s < 4; s++) {
      p0 = MFMA32(kf[0][s], qf[s], p0);
      p1 = MFMA32(kf[1][s], qf[s], p1);
    }

    // online softmax (log2 domain), q = lq lane-local; partner l^32 has other 32 k
    float mx = p0[0];
#pragma unroll
    for (int r = 1; r < 16; r++) mx = fmaxf(mx, p0[r]);
#pragma unroll
    for (int r = 0; r < 16; r++) mx = fmaxf(mx, p1[r]);
    mx = fmaxf(mx, __shfl_xor(mx, 32, 64));
    if (!__all(mx <= m + 10.0f)) {  // defer-max: P bounded by 2^10
      const float mn = fmaxf(m, mx);
      const float al = __builtin_amdgcn_exp2f(m - mn);
      m = mn;
      l *= al;
#pragma unroll
      for (int r = 0; r < 16; r++) { o0[r] *= al; o1[r] *= al; }
    }
    float sum = 0.0f;
#pragma unroll
    for (int r = 0; r < 16; r++) { p0[r] = __builtin_amdgcn_exp2f(p0[r] - m); sum += p0[r]; }
#pragma unroll
    for (int r = 0; r < 16; r++) { p1[r] = __builtin_amdgcn_exp2f(p1[r] - m); sum += p1[r]; }
    l += sum + __shfl_xor(sum, 32, 64);

    // P^T -> bf16 B-frags (in-register)
    bf16x8 pb0, pb1, pb2, pb3;
    MAKE_PB(p0, 0, pb0);
    MAKE_PB(p0, 8, pb1);
    MAKE_PB(p1, 0, pb2);
    MAKE_PB(p1, 8, pb3);

    // PV: O^T += Vt @ P^T
    o0 = MFMA32(vf[0][0], pb0, o0);
    o1 = MFMA32(vf[0][1], pb0, o1);
    o0 = MFMA32(vf[1][0], pb1, o0);
    o1 = MFMA32(vf[1][1], pb1, o1);
    o0 = MFMA32(vf[2][0], pb2, o0);
    o1 = MFMA32(vf[2][1], pb2, o1);
    o0 = MFMA32(vf[3][0], pb3, o0);
    o1 = MFMA32(vf[3][1], pb3, o1);

    buf ^= 1;
  }

  // epilogue: O^T reg r -> d = (r&3) + 8*(r>>2) + 4hi + 32*dblk, q = q0+lq
  const float rl = 1.0f / l;
  u16* op = &O[(size_t)(b * 2048 + q0 + lq) * 1024 + h * 64 + hi * 4];
#pragma unroll
  for (int rq = 0; rq < 4; rq++) {
    ushort4 s0, s1;
    s0.x = f2bf(o0[4 * rq + 0] * rl); s0.y = f2bf(o0[4 * rq + 1] * rl);
    s0.z = f2bf(o0[4 * rq + 2] * rl); s0.w = f2bf(o0[4 * rq + 3] * rl);
    s1.x = f2bf(o1[4 * rq + 0] * rl); s1.y = f2bf(o1[4 * rq + 1] * rl);
    s1.z = f2bf(o1[4 * rq + 2] * rl); s1.w = f2bf(o1[4 * rq + 3] * rl);
    *reinterpret_cast<ushort4*>(&op[rq * 8]) = s0;
    *reinterpret_cast<ushort4*>(&op[rq * 8 + 32]) = s1;
  }
}

extern "C" void kernel_launch(void* const* d_in, const int* in_sizes, int n_in,
                              void* d_out, int out_size, void* d_ws, size_t ws_size,
                              hipStream_t stream) {
  (void)in_sizes; (void)n_in; (void)out_size; (void)ws_size;
  const float* query = (const float*)d_in[0];
  const float* key   = (const float*)d_in[1];
  const float* value = (const float*)d_in[2];
  const float* Wq = (const float*)d_in[3];
  const float* bq = (const float*)d_in[4];
  const float* Wk = (const float*)d_in[5];
  const float* bk = (const float*)d_in[6];
  const float* Wv = (const float*)d_in[7];
  const float* bv = (const float*)d_in[8];
  const float* Wo = (const float*)d_in[9];
  const float* bo = (const float*)d_in[10];

  // Qb (8 MB bf16) in ws; Kb + Vt (16 MB bf16) inside d_out (16 MB fp32),
  // dead until the final fp32 GEMM overwrites it.
  u16* Qb = (u16*)d_ws;
  u16* Kb = (u16*)d_out;
  u16* Vt = (u16*)d_out + 4194304;

  GemmArgs g1;
  g1.A[0] = query; g1.W[0] = Wq; g1.bias[0] = bq; g1.C[0] = Qb; g1.out_mode[0] = 0;
  g1.A[1] = key;   g1.W[1] = Wk; g1.bias[1] = bk; g1.C[1] = Kb; g1.out_mode[1] = 0;
  g1.A[2] = value; g1.W[2] = Wv; g1.bias[2] = bv; g1.C[2] = Vt; g1.out_mode[2] = 1;
  gemm_nt<128, 0><<<dim3(8, 32, 3), dim3(256), 0, stream>>>(g1);

  rope_kernel<<<dim3(4096), dim3(256), 0, stream>>>(Qb, Kb);

  attn_kernel<<<dim3(16, 32), dim3(256), 0, stream>>>(Qb, Kb, Vt, Qb);

  // Final projection: bf16 attn output -> fp32 d_out. BM=64 -> 512 blocks.
  GemmArgs g2;
  for (int i = 0; i < 3; i++) {
    g2.A[i] = Qb; g2.W[i] = Wo; g2.bias[i] = bo;
    g2.C[i] = d_out; g2.out_mode[i] = 2;
  }
  gemm_nt<64, 1><<<dim3(8, 64, 1), dim3(256), 0, stream>>>(g2);
}